// Round 7
// baseline (150.742 us; speedup 1.0000x reference)
//
#include <hip/hip_runtime.h>
#include <math.h>

#define N_TOT 4096   // H*P*D
#define PHO_T 4096   // P*H*OUT_DIM
#define KTOT  40960  // 2*N + 8*N
#define NS    2560   // total k16 steps = KTOT/16

typedef __attribute__((ext_vector_type(8)))  short short8v;  // 8 bf16 (4 VGPRs)
typedef __attribute__((ext_vector_type(16))) float f32x16;   // MFMA 32x32 acc

// global -> LDS direct DMA, 16 B per lane, dest = wave-uniform base + lane*16
#define GLD16(src, dst) __builtin_amdgcn_global_load_lds(                      \
    (const __attribute__((address_space(1))) void*)(src),                      \
    (__attribute__((address_space(3))) void*)(dst), 16, 0, 0)

// f32 -> (hi,lo) bf16, RNE on both (residual exact; dropped lo*lo term is
// zero-mean => no systematic bias in the GEMM)
__device__ __forceinline__ void split1(float x, short& h, short& l) {
    unsigned u  = __builtin_bit_cast(unsigned, x);
    unsigned hu = (u + 0x7FFFu + ((u >> 16) & 1u)) & 0xFFFF0000u;
    h = (short)(hu >> 16);
    float r = x - __builtin_bit_cast(float, hu);     // exact
    unsigned ur = __builtin_bit_cast(unsigned, r);
    l = (short)((ur + 0x7FFFu + ((ur >> 16) & 1u)) >> 16);
}

// ---------------------------------------------------------------------------
// Pass 1: A in MFMA-fragment order, hi/lo bf16 planes; PLUS (fused) the
// ypre init: ypre[b][o] = 2*ss[o]^2*sum_f cb[f][o]  (also resets the
// atomic accumulator every call).
//   fragment stream: for k16-step S, plane p, lane l:
//     Af[((S*2+p)*64 + l)*8 + j] = Act_p[b = l&31][k = S*16 + (l>>5)*8 + j]
// ---------------------------------------------------------------------------
__global__ void act_kernel(const float* __restrict__ q,
                           const float* __restrict__ kx,
                           const float* __restrict__ grid_,
                           const float* __restrict__ coefq,
                           const float* __restrict__ coefk,
                           const float* __restrict__ cb,
                           const float* __restrict__ ssp,
                           short* __restrict__ Af,
                           float* __restrict__ ypre)
{
    const int t = blockIdx.x * 256 + threadIdx.x;  // 163840 = NS * 64
    const int S = t >> 6;
    const int l = t & 63;
    const int b = l & 31;
    const int k0 = S * 16 + (l >> 5) * 8;          // 8-aligned; never crosses a region

    float v[8];
    if (k0 < 8192) {
        const float* src = (k0 < 4096) ? (q  + (size_t)b * N_TOT + k0)
                                       : (kx + (size_t)b * N_TOT + (k0 - 4096));
#pragma unroll
        for (int j = 0; j < 8; ++j) {
            const float x = src[j];
            v[j] = x / (1.f + __expf(-x));
        }
    } else {
        const int f  = (k0 - 8192) >> 12;
        const int n0 = (k0 - 8192) & 4095;         // 8-aligned -> same group for all j
        const int g  = n0 >> 6;
        const float gf  = grid_[f];
        const float cq_ = coefq[g * 8 + f];
        const float ck_ = coefk[g * 8 + f];
        const float* qp = q  + (size_t)b * N_TOT + n0;
        const float* kp = kx + (size_t)b * N_TOT + n0;
#pragma unroll
        for (int j = 0; j < 8; ++j)
            v[j] = __sinf(gf * qp[j]) * cq_ + __sinf(gf * kp[j]) * ck_;
    }

    short8v hi, lo;
#pragma unroll
    for (int j = 0; j < 8; ++j) { short h, lw; split1(v[j], h, lw); hi[j] = h; lo[j] = lw; }
    *(short8v*)&Af[((size_t)(S * 2 + 0) * 64 + l) * 8] = hi;
    *(short8v*)&Af[((size_t)(S * 2 + 1) * 64 + l) * 8] = lo;

    // fused init: first 131072 threads each write one ypre element
    if (t < 32 * PHO_T) {
        const int o = t & 4095;
        const float s = ssp[o];
        float acc = 0.f;
#pragma unroll
        for (int f = 0; f < 8; ++f) acc += cb[f * PHO_T + o];
        ypre[t] = 2.f * s * s * acc;
    }
}

// ---------------------------------------------------------------------------
// Main GEMM via split-bf16 MFMA: y[b][o] += sum_k Act[k][b] * W[k][o]
//   ~ ah*wh + ah*wl + al*wh  (3x mfma_f32_32x32x16_bf16)
// Grid: 32 K-supers (1280 k) x 32 o-blocks (128 o) = 1024 blocks = 4/CU
// (16 waves/CU: 2x the independent HBM streams of r6 at the same 64 KB/CU
// in flight). Block = 4 waves; wave w owns the 32 o-rows [o_base+w*32, +32)
// -> ONE 32x32 MFMA tile (accU/accS pair, 32 acc VGPRs).
// XCD remap: all 32 o-blocks of a k-super share bid%8 -> the shared 160 KB
// Af slice is served from one XCD's L2 (bijective: ks=((bid>>3)&3)*8+(bid&7),
// ob=bid>>5).
// BARRIER-FREE pipeline (LDS is wave-private), per-iteration issue order:
//   [2 Af loads (chunk c)] -> fence -> [4 DMA (chunk c+1)] -> vmcnt(4) -> compute
// vmcnt(4) retires chunk-c DMA + Af while chunk-c+1's 4 DMAs stay in flight
// across the whole compute phase (T3/T4: never drain to 0 in-loop).
// Region resolved per chunk (region-pure, 4096-aligned); conv chunks use
// separate accumulators, scaled by ss^2 in the epilogue.
// W f32 staged with XOR slot swizzle on BOTH sides (rule #21), converted to
// bf16 hi/lo in-register. A read as ready-made fragments (L2-resident).
// ---------------------------------------------------------------------------
#define OBK  128
#define KC   32
#define KSUP 1280
#define NCH  (KSUP / KC)   // 40 chunks per block

__global__ __launch_bounds__(256) void gemm_kernel(
    const float* __restrict__ bwq, const float* __restrict__ bwk,
    const float* __restrict__ cw,  const short* __restrict__ Af,
    const float* __restrict__ ssp, float* __restrict__ ypre)
{
    __shared__ float Wl[2][OBK * KC];   // 2 * 16 KB = 32 KB

    const int t   = threadIdx.x;
    const int bid = blockIdx.x;                    // 0..1023
    const int ks  = ((bid >> 3) & 3) * 8 + (bid & 7);  // 0..31, const per bid%8
    const int ob  = bid >> 5;                      // 0..31
    const int o_base = ob * OBK;
    const int k_base = ks * KSUP;

    const int w  = t >> 6;   // wave 0..3
    const int l  = t & 63;   // lane
    const int srow  = l >> 3;
    const int sslot = (l & 7) ^ (srow & 7);   // DMA source swizzle (rule #21)

    f32x16 accU, accS;
#pragma unroll
    for (int i = 0; i < 16; ++i) { accU[i] = 0.f; accS[i] = 0.f; }

    // weight row-pointer for global k index kg (chunk-uniform)
    auto wptr = [&](int kg) -> const float* {
        if (kg < 4096)  return bwq + kg;
        if (kg < 8192)  return bwk + (kg - 4096);
        const int f    = (kg - 8192) >> 12;
        const int noff = (kg - 8192) & 4095;
        return cw + (size_t)f * (size_t)PHO_T * N_TOT + noff;
    };

    // stage the 32-k chunk at global k kg into buffer buf (4 DMA instrs/wave;
    // wave w writes rows w*32 .. w*32+31 only -> wave-private)
    auto stage = [&](int kg, int buf) {
        const float* Wp = wptr(kg);
#pragma unroll
        for (int i = 0; i < 4; ++i) {
            const int row = w * 32 + i * 8 + srow;
            const float* src = Wp + (size_t)(o_base + row) * N_TOT + sslot * 4;
            GLD16(src, &Wl[buf][(w * 32 + i * 8) * KC]);
        }
    };

    const int rkey = l & 7;              // row&7 (row0 = w*32 + (l&31), 32|w*32)
    const int row0 = w * 32 + (l & 31);
    const int j0b  = (l >> 5) * 2;

    // compute chunk (kg, buffer cur) from LDS + prefetched A fragments
    auto compute = [&](int kg, int cur, const short8v& ah0, const short8v& al0,
                       const short8v& ah1, const short8v& al1) {
        const bool sc = (kg >= 8192);    // conv region -> scaled accumulator
#pragma unroll
        for (int s = 0; s < 2; ++s) {
            const short8v& ah = s ? ah1 : ah0;
            const short8v& al = s ? al1 : al0;
            const int j0 = s * 4 + j0b;

            const float* rp = &Wl[cur][row0 * KC];
            const float4 wa = *(const float4*)&rp[((j0    ) ^ rkey) * 4];
            const float4 wb = *(const float4*)&rp[((j0 + 1) ^ rkey) * 4];
            short8v bh, bl;
            {
                short h, lw;
                split1(wa.x, h, lw); bh[0] = h; bl[0] = lw;
                split1(wa.y, h, lw); bh[1] = h; bl[1] = lw;
                split1(wa.z, h, lw); bh[2] = h; bl[2] = lw;
                split1(wa.w, h, lw); bh[3] = h; bl[3] = lw;
                split1(wb.x, h, lw); bh[4] = h; bl[4] = lw;
                split1(wb.y, h, lw); bh[5] = h; bl[5] = lw;
                split1(wb.z, h, lw); bh[6] = h; bl[6] = lw;
                split1(wb.w, h, lw); bh[7] = h; bl[7] = lw;
            }
            f32x16& acc = sc ? accS : accU;        // wave-uniform select
            acc = __builtin_amdgcn_mfma_f32_32x32x16_bf16(ah, bh, acc, 0, 0, 0);
            acc = __builtin_amdgcn_mfma_f32_32x32x16_bf16(ah, bl, acc, 0, 0, 0);
            acc = __builtin_amdgcn_mfma_f32_32x32x16_bf16(al, bh, acc, 0, 0, 0);
        }
    };

    // prologue: chunk 0 DMA in flight
    stage(k_base, 0);

    short8v ah0, al0, ah1, al1;
    for (int c = 0; c < NCH - 1; ++c) {
        const int cur = c & 1;
        const int kg  = k_base + c * KC;
        const size_t Sg = (size_t)(kg >> 4);
        // A fragments for chunk c (issued BEFORE next chunk's DMA)
        ah0 = *(const short8v*)&Af[(((Sg    ) * 2 + 0) * 64 + l) * 8];
        al0 = *(const short8v*)&Af[(((Sg    ) * 2 + 1) * 64 + l) * 8];
        ah1 = *(const short8v*)&Af[(((Sg + 1) * 2 + 0) * 64 + l) * 8];
        al1 = *(const short8v*)&Af[(((Sg + 1) * 2 + 1) * 64 + l) * 8];
        asm volatile("" ::: "memory");            // pin Af loads above the DMAs
        stage(kg + KC, cur ^ 1);                  // chunk c+1 DMA, stays in flight
        asm volatile("s_waitcnt vmcnt(4)" ::: "memory");  // chunk c + Af landed
        __builtin_amdgcn_sched_barrier(0);
        compute(kg, cur, ah0, al0, ah1, al1);
    }
    {   // peeled last chunk: drain everything
        const int c   = NCH - 1;
        const int kg  = k_base + c * KC;
        const size_t Sg = (size_t)(kg >> 4);
        ah0 = *(const short8v*)&Af[(((Sg    ) * 2 + 0) * 64 + l) * 8];
        al0 = *(const short8v*)&Af[(((Sg    ) * 2 + 1) * 64 + l) * 8];
        ah1 = *(const short8v*)&Af[(((Sg + 1) * 2 + 0) * 64 + l) * 8];
        al1 = *(const short8v*)&Af[(((Sg + 1) * 2 + 1) * 64 + l) * 8];
        asm volatile("s_waitcnt vmcnt(0)" ::: "memory");
        __builtin_amdgcn_sched_barrier(0);
        compute(kg, c & 1, ah0, al0, ah1, al1);
    }

    // epilogue: D layout (32x32): col = l&31, row(b) = (r&3) + 8*(r>>2) + 4*(l>>5)
    const int o0 = o_base + w * 32 + (l & 31);
    const float x0 = ssp[o0];
    const float s0 = x0 * x0;
    const int bh4 = 4 * (l >> 5);
#pragma unroll
    for (int r = 0; r < 16; ++r) {
        const int b = (r & 3) + 8 * (r >> 2) + bh4;
        atomicAdd(&ypre[(size_t)b * PHO_T + o0], accU[r] + accS[r] * s0);
    }
}

// ---------------------------------------------------------------------------
// Softmax over the last dim (32): rows of 32 contiguous elements.
// ---------------------------------------------------------------------------
__global__ void softmax_kernel(const float* __restrict__ yp,
                               float* __restrict__ out)
{
    const int t  = threadIdx.x;
    const int r  = blockIdx.x * 8 + (t >> 5);  // 4096 rows
    const int od = t & 31;
    const float v = yp[(size_t)r * 32 + od];
    float m = v;
#pragma unroll
    for (int s = 16; s > 0; s >>= 1) m = fmaxf(m, __shfl_xor(m, s, 32));
    const float e = __expf(v - m);
    float sum = e;
#pragma unroll
    for (int s = 16; s > 0; s >>= 1) sum += __shfl_xor(sum, s, 32);
    out[(size_t)r * 32 + od] = e / sum;
}

// ---------------------------------------------------------------------------
extern "C" void kernel_launch(void* const* d_in, const int* in_sizes, int n_in,
                              void* d_out, int out_size, void* d_ws, size_t ws_size,
                              hipStream_t stream)
{
    const float* q    = (const float*)d_in[0];
    const float* k    = (const float*)d_in[1];
    const float* grid = (const float*)d_in[2];
    const float* bwq  = (const float*)d_in[3];
    const float* bwk  = (const float*)d_in[4];
    const float* cq   = (const float*)d_in[5];
    const float* ck   = (const float*)d_in[6];
    const float* cw   = (const float*)d_in[7];
    const float* cb   = (const float*)d_in[8];
    const float* ssp  = (const float*)d_in[9];
    float* out = (float*)d_out;

    short* Af   = (short*)d_ws;                                   // NS*2*64*8 shorts = 5242880 B
    float* ypre = (float*)((char*)d_ws + (size_t)NS * 2 * 64 * 16); // 131072*4 = 524288 B

    act_kernel<<<640, 256, 0, stream>>>(q, k, grid, cq, ck, cb, ssp, Af, ypre);
    gemm_kernel<<<1024, 256, 0, stream>>>(bwq, bwk, cw, Af, ssp, ypre);
    softmax_kernel<<<512, 256, 0, stream>>>(ypre, out);
}

// Round 8
// 141.344 us; speedup vs baseline: 1.0665x; 1.0665x over previous
//
#include <hip/hip_runtime.h>
#include <math.h>

#define N_TOT 4096   // H*P*D
#define PHO_T 4096   // P*H*OUT_DIM
#define KTOT  40960  // 2*N + 8*N
#define NS    2560   // total k16 steps = KTOT/16
#define NSUP  32     // k-supers (partial slices)

typedef __attribute__((ext_vector_type(8)))  short short8v;  // 8 bf16 (4 VGPRs)
typedef __attribute__((ext_vector_type(16))) float f32x16;   // MFMA 32x32 acc

// global -> LDS direct DMA, 16 B per lane, dest = wave-uniform base + lane*16
#define GLD16(src, dst) __builtin_amdgcn_global_load_lds(                      \
    (const __attribute__((address_space(1))) void*)(src),                      \
    (__attribute__((address_space(3))) void*)(dst), 16, 0, 0)

// f32 -> (hi,lo) bf16, RNE on both (residual exact; dropped lo*lo term is
// zero-mean => no systematic bias in the GEMM)
__device__ __forceinline__ void split1(float x, short& h, short& l) {
    unsigned u  = __builtin_bit_cast(unsigned, x);
    unsigned hu = (u + 0x7FFFu + ((u >> 16) & 1u)) & 0xFFFF0000u;
    h = (short)(hu >> 16);
    float r = x - __builtin_bit_cast(float, hu);     // exact
    unsigned ur = __builtin_bit_cast(unsigned, r);
    l = (short)((ur + 0x7FFFu + ((ur >> 16) & 1u)) >> 16);
}

// ---------------------------------------------------------------------------
// Pass 1: A in MFMA-fragment order, hi/lo bf16 planes.
//   fragment stream: for k16-step S, plane p, lane l:
//     Af[((S*2+p)*64 + l)*8 + j] = Act_p[b = l&31][k = S*16 + (l>>5)*8 + j]
// ---------------------------------------------------------------------------
__global__ void act_kernel(const float* __restrict__ q,
                           const float* __restrict__ kx,
                           const float* __restrict__ grid_,
                           const float* __restrict__ coefq,
                           const float* __restrict__ coefk,
                           short* __restrict__ Af)
{
    const int t = blockIdx.x * 256 + threadIdx.x;  // 163840 = NS * 64
    const int S = t >> 6;
    const int l = t & 63;
    const int b = l & 31;
    const int k0 = S * 16 + (l >> 5) * 8;          // 8-aligned; never crosses a region

    float v[8];
    if (k0 < 8192) {
        const float* src = (k0 < 4096) ? (q  + (size_t)b * N_TOT + k0)
                                       : (kx + (size_t)b * N_TOT + (k0 - 4096));
#pragma unroll
        for (int j = 0; j < 8; ++j) {
            const float x = src[j];
            v[j] = x / (1.f + __expf(-x));
        }
    } else {
        const int f  = (k0 - 8192) >> 12;
        const int n0 = (k0 - 8192) & 4095;         // 8-aligned -> same group for all j
        const int g  = n0 >> 6;
        const float gf  = grid_[f];
        const float cq_ = coefq[g * 8 + f];
        const float ck_ = coefk[g * 8 + f];
        const float* qp = q  + (size_t)b * N_TOT + n0;
        const float* kp = kx + (size_t)b * N_TOT + n0;
#pragma unroll
        for (int j = 0; j < 8; ++j)
            v[j] = __sinf(gf * qp[j]) * cq_ + __sinf(gf * kp[j]) * ck_;
    }

    short8v hi, lo;
#pragma unroll
    for (int j = 0; j < 8; ++j) { short h, lw; split1(v[j], h, lw); hi[j] = h; lo[j] = lw; }
    *(short8v*)&Af[((size_t)(S * 2 + 0) * 64 + l) * 8] = hi;
    *(short8v*)&Af[((size_t)(S * 2 + 1) * 64 + l) * 8] = lo;
}

// ---------------------------------------------------------------------------
// Main GEMM via split-bf16 MFMA: ypart[ks][b][o] = sum_{k in super ks}
//   Act[k][b] * W[k][o]   (~ ah*wh + ah*wl + al*wh, 3x mfma_f32_32x32x16_bf16)
// Grid: 32 K-supers (1280 k) x 16 o-blocks (256 o) = 512 blocks = 2/CU,
// one co-resident generation (r6 geometry — r7's 128-o split regressed).
// BARRIER-FREE pipeline: each wave's MFMA tiles read ONLY the 64 LDS rows
// that wave DMAs itself (LDS is wave-private) -> no __syncthreads at all.
// Per-iteration issue order (vmcnt is one in-order counter!):
//   [4 Af loads (chunk c)] -> fence -> [8 DMA (chunk c+1)] -> vmcnt(8) -> compute
// vmcnt(8) retires chunk-c DMA + Af loads while keeping chunk-c+1's 8 DMAs
// in flight across the whole compute phase (T3/T4: never drain to 0 in-loop).
// Epilogue: DETERMINISTIC partial stores into the k-super's private slice
// (replaces 4.2M serialized atomicAdds — no RMW burst at block retirement).
// Region (bwq/bwk/conv) resolved per chunk (region-pure, 4096-aligned);
// conv chunks use separate accumulators, scaled by ss^2 in the epilogue.
// W f32 staged with XOR slot swizzle on BOTH sides (rule #21), converted to
// bf16 hi/lo in-register. A read as ready-made fragments (L1/L2-resident).
// ---------------------------------------------------------------------------
#define OBK  256
#define KC   32
#define KSUP 1280
#define NCH  (KSUP / KC)   // 40 chunks per block

__global__ __launch_bounds__(256) void gemm_kernel(
    const float* __restrict__ bwq, const float* __restrict__ bwk,
    const float* __restrict__ cw,  const short* __restrict__ Af,
    const float* __restrict__ ssp, float* __restrict__ ypart)
{
    __shared__ float Wl[2][OBK * KC];   // 2 * 32 KB

    const int t  = threadIdx.x;
    const int ks = blockIdx.x >> 4;      // 0..31
    const int ob = blockIdx.x & 15;      // 0..15
    const int o_base = ob * OBK;
    const int k_base = ks * KSUP;

    const int w  = t >> 6;   // wave 0..3
    const int l  = t & 63;   // lane
    const int srow  = l >> 3;
    const int sslot = (l & 7) ^ (srow & 7);   // DMA source swizzle (rule #21)

    f32x16 accU0, accU1, accS0, accS1;
#pragma unroll
    for (int i = 0; i < 16; ++i) {
        accU0[i] = 0.f; accU1[i] = 0.f; accS0[i] = 0.f; accS1[i] = 0.f;
    }

    // weight row-pointer for global k index kg (chunk-uniform)
    auto wptr = [&](int kg) -> const float* {
        if (kg < 4096)  return bwq + kg;
        if (kg < 8192)  return bwk + (kg - 4096);
        const int f    = (kg - 8192) >> 12;
        const int noff = (kg - 8192) & 4095;
        return cw + (size_t)f * (size_t)PHO_T * N_TOT + noff;
    };

    // stage the 32-k chunk at global k kg into buffer buf (8 DMA instrs/wave;
    // wave w writes rows w*64 .. w*64+63 only -> wave-private)
    auto stage = [&](int kg, int buf) {
        const float* Wp = wptr(kg);
#pragma unroll
        for (int i = 0; i < 8; ++i) {
            const int row = w * 64 + i * 8 + srow;
            const float* src = Wp + (size_t)(o_base + row) * N_TOT + sslot * 4;
            GLD16(src, &Wl[buf][(w * 64 + i * 8) * KC]);
        }
    };

    const int rkey = l & 7;              // row&7 for both tiles (nt*32 = 0 mod 8)
    const int row0 = w * 64 + (l & 31);
    const int j0b  = (l >> 5) * 2;

    // compute chunk (kg, buffer cur) from LDS + prefetched A fragments
    auto compute = [&](int kg, int cur, const short8v& ah0, const short8v& al0,
                       const short8v& ah1, const short8v& al1) {
        const bool sc = (kg >= 8192);    // conv region -> scaled accumulators
#pragma unroll
        for (int s = 0; s < 2; ++s) {
            const short8v& ah = s ? ah1 : ah0;
            const short8v& al = s ? al1 : al0;
            const int j0 = s * 4 + j0b;

            auto tileop = [&](int nt, f32x16& acc) {
                const float* rp = &Wl[cur][(row0 + nt * 32) * KC];
                const float4 wa = *(const float4*)&rp[((j0    ) ^ rkey) * 4];
                const float4 wb = *(const float4*)&rp[((j0 + 1) ^ rkey) * 4];
                short8v bh, bl;
                {
                    short h, lw;
                    split1(wa.x, h, lw); bh[0] = h; bl[0] = lw;
                    split1(wa.y, h, lw); bh[1] = h; bl[1] = lw;
                    split1(wa.z, h, lw); bh[2] = h; bl[2] = lw;
                    split1(wa.w, h, lw); bh[3] = h; bl[3] = lw;
                    split1(wb.x, h, lw); bh[4] = h; bl[4] = lw;
                    split1(wb.y, h, lw); bh[5] = h; bl[5] = lw;
                    split1(wb.z, h, lw); bh[6] = h; bl[6] = lw;
                    split1(wb.w, h, lw); bh[7] = h; bl[7] = lw;
                }
                acc = __builtin_amdgcn_mfma_f32_32x32x16_bf16(ah, bh, acc, 0, 0, 0);
                acc = __builtin_amdgcn_mfma_f32_32x32x16_bf16(ah, bl, acc, 0, 0, 0);
                acc = __builtin_amdgcn_mfma_f32_32x32x16_bf16(al, bh, acc, 0, 0, 0);
            };
            if (sc) { tileop(0, accS0); tileop(1, accS1); }   // wave-uniform branch,
            else    { tileop(0, accU0); tileop(1, accU1); }   // static acc targets
        }
    };

    // prologue: chunk 0 DMA in flight
    stage(k_base, 0);

    short8v ah0, al0, ah1, al1;
    for (int c = 0; c < NCH - 1; ++c) {
        const int cur = c & 1;
        const int kg  = k_base + c * KC;
        const size_t Sg = (size_t)(kg >> 4);
        // A fragments for chunk c (issued BEFORE next chunk's DMA)
        ah0 = *(const short8v*)&Af[(((Sg    ) * 2 + 0) * 64 + l) * 8];
        al0 = *(const short8v*)&Af[(((Sg    ) * 2 + 1) * 64 + l) * 8];
        ah1 = *(const short8v*)&Af[(((Sg + 1) * 2 + 0) * 64 + l) * 8];
        al1 = *(const short8v*)&Af[(((Sg + 1) * 2 + 1) * 64 + l) * 8];
        asm volatile("" ::: "memory");            // pin Af loads above the DMAs
        stage(kg + KC, cur ^ 1);                  // chunk c+1 DMA, stays in flight
        asm volatile("s_waitcnt vmcnt(8)" ::: "memory");  // chunk c + Af landed
        __builtin_amdgcn_sched_barrier(0);
        compute(kg, cur, ah0, al0, ah1, al1);
    }
    {   // peeled last chunk: drain everything
        const int c   = NCH - 1;
        const int kg  = k_base + c * KC;
        const size_t Sg = (size_t)(kg >> 4);
        ah0 = *(const short8v*)&Af[(((Sg    ) * 2 + 0) * 64 + l) * 8];
        al0 = *(const short8v*)&Af[(((Sg    ) * 2 + 1) * 64 + l) * 8];
        ah1 = *(const short8v*)&Af[(((Sg + 1) * 2 + 0) * 64 + l) * 8];
        al1 = *(const short8v*)&Af[(((Sg + 1) * 2 + 1) * 64 + l) * 8];
        asm volatile("s_waitcnt vmcnt(0)" ::: "memory");
        __builtin_amdgcn_sched_barrier(0);
        compute(kg, c & 1, ah0, al0, ah1, al1);
    }

    // epilogue: deterministic partial stores into this k-super's slice.
    // D layout (32x32): col = l&31, row(b) = (r&3) + 8*(r>>2) + 4*(l>>5)
    float* __restrict__ yp = ypart + (size_t)ks * (32 * PHO_T);
    const int o0 = o_base + w * 64 + (l & 31);
    const int o1 = o0 + 32;
    const float x0 = ssp[o0], x1 = ssp[o1];
    const float s0 = x0 * x0, s1 = x1 * x1;
    const int bh4 = 4 * (l >> 5);
#pragma unroll
    for (int r = 0; r < 16; ++r) {
        const int b = (r & 3) + 8 * (r >> 2) + bh4;
        yp[(size_t)b * PHO_T + o0] = accU0[r] + accS0[r] * s0;
        yp[(size_t)b * PHO_T + o1] = accU1[r] + accS1[r] * s1;
    }
}

// ---------------------------------------------------------------------------
// Reduce the 32 partial slices + bias term, then softmax over the last dim
// (32 contiguous elements per row). One 32-lane group per row; element
// index e = b*4096+o, so 32 consecutive threads = one softmax row.
// bias = 2*ss[o]^2 * sum_f cb[f][o]  (absorbs the old init kernel).
// ---------------------------------------------------------------------------
__global__ void reduce_softmax_kernel(const float* __restrict__ ypart,
                                      const float* __restrict__ cb,
                                      const float* __restrict__ ssp,
                                      float* __restrict__ out)
{
    const int e = blockIdx.x * 256 + threadIdx.x;  // 131072 = 32*4096
    const int o = e & 4095;

    float v = 0.f;
#pragma unroll
    for (int ks = 0; ks < NSUP; ++ks)
        v += ypart[(size_t)ks * (32 * PHO_T) + e];

    float bias = 0.f;
#pragma unroll
    for (int f = 0; f < 8; ++f) bias += cb[f * PHO_T + o];
    const float ss = ssp[o];
    v += 2.f * ss * ss * bias;

    float m = v;
#pragma unroll
    for (int s = 16; s > 0; s >>= 1) m = fmaxf(m, __shfl_xor(m, s, 32));
    const float ex = __expf(v - m);
    float sum = ex;
#pragma unroll
    for (int s = 16; s > 0; s >>= 1) sum += __shfl_xor(sum, s, 32);
    out[e] = ex / sum;
}

// ---------------------------------------------------------------------------
extern "C" void kernel_launch(void* const* d_in, const int* in_sizes, int n_in,
                              void* d_out, int out_size, void* d_ws, size_t ws_size,
                              hipStream_t stream)
{
    const float* q    = (const float*)d_in[0];
    const float* k    = (const float*)d_in[1];
    const float* grid = (const float*)d_in[2];
    const float* bwq  = (const float*)d_in[3];
    const float* bwk  = (const float*)d_in[4];
    const float* cq   = (const float*)d_in[5];
    const float* ck   = (const float*)d_in[6];
    const float* cw   = (const float*)d_in[7];
    const float* cb   = (const float*)d_in[8];
    const float* ssp  = (const float*)d_in[9];
    float* out = (float*)d_out;

    short* Af    = (short*)d_ws;                                // NS*2*64*8 shorts = 5242880 B
    float* ypart = (float*)((char*)d_ws + (size_t)NS * 2 * 64 * 16);
    // ypart: NSUP * 131072 * 4 B = 16777216 B  (total ws use ~22 MB)

    act_kernel<<<640, 256, 0, stream>>>(q, k, grid, cq, ck, Af);
    gemm_kernel<<<512, 256, 0, stream>>>(bwq, bwk, cw, Af, ssp, ypart);
    reduce_softmax_kernel<<<512, 256, 0, stream>>>(ypart, cb, ssp, out);
}